// Round 14
// baseline (103907.764 us; speedup 1.0000x reference)
//
#include <hip/hip_runtime.h>
#include <math.h>

#define OUTER_SWEEPS 12
#define INNER_SWEEPS 4
// JAX pinv default: rcond = 10 * max(M,N) * eps_f32 = 10*512*2^-23
#define JAX_RTOL 6.103515625e-4

__device__ __forceinline__ double dmx(double a, double b){ return a>b?a:b; }

__global__ void mk5_diag(float* out, int n, float val)
{
    int i = blockIdx.x * blockDim.x + threadIdx.x;
    if (i < n) out[i] = val;
}

// --------------------------------------------------------------------------
// Z, b, cM, cK (one block, 256 threads, fp64, f32 inputs)
// --------------------------------------------------------------------------
__global__ void mk5_zb(const float* S,
                       const float* WZ1, const float* bZ1,
                       const float* WZ2, const float* bZ2,
                       const float* WB1, const float* bB1,
                       const float* WB2, const float* bB2,
                       const float* WM1, const float* bM1,
                       const float* WK1, const float* bK1,
                       double* Z, double* cM, double* cK, double* bout)
{
    __shared__ double sS[1536];
    __shared__ double hbar[256];
    __shared__ double Zs[256];
    __shared__ double red[256];
    int t = threadIdx.x;
    for (int i = t; i < 1536; i += 256) sS[i] = (double)S[i];
    __syncthreads();

    double w0 = (double)WZ1[t], w1 = (double)WZ1[256 + t], w2 = (double)WZ1[512 + t];
    double bb = (double)bZ1[t];
    double acc = 0.0;
    for (int i = 0; i < 512; ++i) {
        double a = sS[3 * i] * w0 + sS[3 * i + 1] * w1 + sS[3 * i + 2] * w2 + bb;
        if (a > 0.0) acc += a;
    }
    hbar[t] = acc * (1.0 / 512.0);
    __syncthreads();

    double z = (double)bZ2[t];
    for (int k = 0; k < 256; ++k) z += hbar[k] * (double)WZ2[k * 256 + t];
    Zs[t] = z; Z[t] = z;
    __syncthreads();

    double a = (double)bB1[t];
    for (int k = 0; k < 256; ++k) a += Zs[k] * (double)WB1[k * 256 + t];
    double h = (a > 0.0) ? a : 0.0;
    red[t] = h * (double)WB2[t];
    __syncthreads();
    for (int s = 128; s > 0; s >>= 1) { if (t < s) red[t] += red[t + s]; __syncthreads(); }
    if (t == 0) bout[0] = red[0] + (double)bB2[0];

    double m = (double)bM1[t];
    for (int k = 0; k < 256; ++k) m += Zs[k] * (double)WM1[(2 + k) * 256 + t];
    cM[t] = m;
    double kk = (double)bK1[t];
    for (int k = 0; k < 256; ++k) kk += Zs[k] * (double)WK1[(2 + k) * 256 + t];
    cK[t] = kk;
}

// --------------------------------------------------------------------------
// per support row: rhs (f64), Ks (f32 storage), ||Ks||^2 (f64)
// --------------------------------------------------------------------------
__global__ void mk5_support(const float* S,
                            const float* WM1, const float* WM2, const float* bM2,
                            const float* WK1, const float* WK2, const float* bK2,
                            const double* cM, const double* cK,
                            float* Ksf, double* nKs, double* rhs)
{
    int i = blockIdx.x;
    int t = threadIdx.x;
    __shared__ double hK[256];
    __shared__ double red[256];
    double x0 = (double)S[3 * i], x1 = (double)S[3 * i + 1], sy = (double)S[3 * i + 2];

    double aM = x0 * (double)WM1[t] + x1 * (double)WM1[256 + t] + cM[t];
    double hM = (aM > 0.0) ? aM : 0.0;
    red[t] = hM * (double)WM2[t];
    double aK = x0 * (double)WK1[t] + x1 * (double)WK1[256 + t] + cK[t];
    hK[t] = (aK > 0.0) ? aK : 0.0;
    __syncthreads();
    for (int s = 128; s > 0; s >>= 1) { if (t < s) red[t] += red[t + s]; __syncthreads(); }
    if (t == 0) rhs[i] = sy - (red[0] + (double)bM2[0]);
    __syncthreads();

    double acc = (double)bK2[t];
    for (int k = 0; k < 256; ++k) acc += hK[k] * (double)WK2[k * 256 + t];
    float kf = (float)acc;
    Ksf[i * 256 + t] = kf;
    double kd = (double)kf;
    red[t] = kd * kd;
    __syncthreads();
    for (int s = 128; s > 0; s >>= 1) { if (t < s) red[t] += red[t + s]; __syncthreads(); }
    if (t == 0) nKs[i] = red[0];
}

// --------------------------------------------------------------------------
// self_k matrix A (fp64 512x512)
// --------------------------------------------------------------------------
__global__ void mk5_selfA(const float* S, const float* Ksf,
                          const double* nKs, const double* bptr, double* A)
{
    int i = blockIdx.x;
    int t = threadIdx.x;
    __shared__ double Ki[256];
    Ki[t] = (double)Ksf[i * 256 + t];
    __syncthreads();
    double b = bptr[0];
    double ni = nKs[i];
    float sxi0 = S[3 * i], sxi1 = S[3 * i + 1];
    for (int j = t; j < 512; j += 256) {
        const float* kr = &Ksf[j * 256];
        double dot = 0.0;
        for (int k = 0; k < 256; ++k) dot += Ki[k] * (double)kr[k];
        double d2 = ni + nKs[j] - 2.0 * dot;
        double d = sqrt(dmx(d2, 0.0));
        double val = exp(-d);
        if (sxi0 == S[3 * j] && sxi1 == S[3 * j + 1]) val += b;
        A[i * 512 + j] = val;
    }
}

// --------------------------------------------------------------------------
__global__ void ej_vinit(double* V)
{
    int i = blockIdx.x * blockDim.x + threadIdx.x;
    if (i < 512 * 512) V[i] = ((i >> 9) == (i & 511)) ? 1.0 : 0.0;
}

__device__ __forceinline__ void outer_pair(int r, int k, int* I, int* J)
{
    *I = (k == 0) ? 0 : (1 + (k - 1 + r) % 15);
    *J = 1 + (14 - k + r) % 15;
}

__global__ void __launch_bounds__(512)
ej_sub(const double* A, double* Qg, const int r)
{
    __shared__ double S[64][65];
    __shared__ double Q[64][65];
    __shared__ int    pp[32], pq[32];
    __shared__ double pc[32], ps[32];
    int k = blockIdx.x, t = threadIdx.x;
    int I, J; outer_pair(r, k, &I, &J);

    for (int e = t; e < 4096; e += 512) {
        int i = e >> 6, j = e & 63;
        int gi = (i < 32) ? (I * 32 + i) : (J * 32 + i - 32);
        int gj = (j < 32) ? (I * 32 + j) : (J * 32 + j - 32);
        S[i][j] = A[gi * 512 + gj];
        Q[i][j] = (i == j) ? 1.0 : 0.0;
    }
    __syncthreads();

    for (int sw = 0; sw < INNER_SWEEPS; ++sw)
    for (int rr = 0; rr < 63; ++rr) {
        if (t < 32) {
            int p = (t == 0) ? 0 : (1 + (t - 1 + rr) % 63);
            int q = 1 + (62 - t + rr) % 63;
            if (p > q) { int tmp = p; p = q; q = tmp; }
            pp[t] = p; pq[t] = q;
            double app = S[p][p], aqq = S[q][q], apq = S[p][q];
            double c = 1.0, s = 0.0;
            if (fabs(apq) > 1e-15 * (fabs(app) + fabs(aqq)) + 1e-300) {
                double tau = (aqq - app) / (2.0 * apq);
                double tt = (tau >= 0.0 ? 1.0 : -1.0) / (fabs(tau) + sqrt(1.0 + tau * tau));
                c = 1.0 / sqrt(1.0 + tt * tt);
                s = tt * c;
            }
            pc[t] = c; ps[t] = s;
        }
        __syncthreads();
        for (int e = t; e < 2048; e += 512) {
            int pr = e >> 6, j = e & 63;
            double s_ = ps[pr];
            if (s_ != 0.0) {
                double c_ = pc[pr]; int p = pp[pr], q = pq[pr];
                double a = S[p][j], bv = S[q][j];
                S[p][j] = c_ * a - s_ * bv;
                S[q][j] = s_ * a + c_ * bv;
            }
        }
        __syncthreads();
        for (int e = t; e < 4096; e += 512) {
            int pr = (e >> 6) & 31, i = e & 63, isQ = e >> 11;
            double s_ = ps[pr];
            if (s_ != 0.0) {
                double c_ = pc[pr]; int p = pp[pr], q = pq[pr];
                if (isQ == 0) {
                    double a = S[i][p], bv = S[i][q];
                    S[i][p] = c_ * a - s_ * bv;
                    S[i][q] = s_ * a + c_ * bv;
                } else {
                    double a = Q[i][p], bv = Q[i][q];
                    Q[i][p] = c_ * a - s_ * bv;
                    Q[i][q] = s_ * a + c_ * bv;
                }
            }
        }
        __syncthreads();
    }
    for (int e = t; e < 4096; e += 512) Qg[k * 4096 + e] = Q[e >> 6][e & 63];
}

__global__ void __launch_bounds__(256)
ej_rows(double* A, const double* Qg, const int r)
{
    __shared__ double Q[64][65];
    __shared__ double T[64][33];
    int k = blockIdx.x, ct = blockIdx.y, t = threadIdx.x;
    int I, J; outer_pair(r, k, &I, &J);
    for (int e = t; e < 4096; e += 256) Q[e >> 6][e & 63] = Qg[k * 4096 + e];
    for (int e = t; e < 2048; e += 256) {
        int m = e >> 5, c = e & 31;
        int gm = (m < 32) ? (I * 32 + m) : (J * 32 + m - 32);
        T[m][c] = A[gm * 512 + ct * 32 + c];
    }
    __syncthreads();
    int rr_ = t & 63, c0 = (t >> 6) * 8;
    double acc[8] = {0, 0, 0, 0, 0, 0, 0, 0};
    for (int m = 0; m < 64; ++m) {
        double qm = Q[m][rr_];
        #pragma unroll
        for (int cc = 0; cc < 8; ++cc) acc[cc] += qm * T[m][c0 + cc];
    }
    int gr = (rr_ < 32) ? (I * 32 + rr_) : (J * 32 + rr_ - 32);
    #pragma unroll
    for (int cc = 0; cc < 8; ++cc) A[gr * 512 + ct * 32 + c0 + cc] = acc[cc];
}

__global__ void __launch_bounds__(256)
ej_cols(double* A, double* V, const double* Qg, const int r)
{
    __shared__ double Q[64][65];
    __shared__ double T[32][65];
    int k = blockIdx.x, rt = blockIdx.y, t = threadIdx.x;
    int I, J; outer_pair(r, k, &I, &J);
    for (int e = t; e < 4096; e += 256) Q[e >> 6][e & 63] = Qg[k * 4096 + e];

    for (int pass = 0; pass < 2; ++pass) {
        double* M = pass ? V : A;
        __syncthreads();
        for (int e = t; e < 2048; e += 256) {
            int rr_ = e >> 6, m = e & 63;
            int gm = (m < 32) ? (I * 32 + m) : (J * 32 + m - 32);
            T[rr_][m] = M[(rt * 32 + rr_) * 512 + gm];
        }
        __syncthreads();
        int rr_ = t & 31, c0 = (t >> 5) * 8;
        double acc[8] = {0, 0, 0, 0, 0, 0, 0, 0};
        for (int m = 0; m < 64; ++m) {
            double tv = T[rr_][m];
            #pragma unroll
            for (int cc = 0; cc < 8; ++cc) acc[cc] += tv * Q[m][c0 + cc];
        }
        #pragma unroll
        for (int cc = 0; cc < 8; ++cc) {
            int c = c0 + cc;
            int gc = (c < 32) ? (I * 32 + c) : (J * 32 + c - 32);
            M[(rt * 32 + rr_) * 512 + gc] = acc[cc];
        }
    }
}

// --------------------------------------------------------------------------
// assemble with JAX pinv truncation rule: cutoff = 10*512*eps_f32 * sigma_max
// --------------------------------------------------------------------------
__global__ void __launch_bounds__(512)
ej_assemble(const double* A, const double* V, const double* rhs,
            double* v, double* flag)
{
    __shared__ double coef[512];
    __shared__ double red[512];
    int t = threadIdx.x;
    double lt = A[t * 513];

    double off = 0.0;
    const double* row = &A[t * 512];
    for (int j = 0; j < 512; ++j) { double a = row[j]; off += a * a; }
    double dg = lt * lt;
    off -= dg;

    red[t] = fabs(lt);
    __syncthreads();
    for (int s = 256; s > 0; s >>= 1) { if (t < s) red[t] = dmx(red[t], red[t + s]); __syncthreads(); }
    double lmax = red[0];
    __syncthreads();

    double cutoff = JAX_RTOL * lmax;

    double w = 0.0;
    for (int k = 0; k < 512; ++k) w += V[k * 512 + t] * rhs[k];
    int keep = (fabs(lt) > cutoff) ? 1 : 0;
    coef[t] = keep ? (w / lt) : 0.0;

    red[t] = (double)keep;
    __syncthreads();
    for (int s = 256; s > 0; s >>= 1) { if (t < s) red[t] += red[t + s]; __syncthreads(); }
    double nk = red[0];
    __syncthreads();

    red[t] = off;
    __syncthreads();
    for (int s = 256; s > 0; s >>= 1) { if (t < s) red[t] += red[t + s]; __syncthreads(); }
    double offsum = red[0];
    __syncthreads();
    red[t] = dg;
    __syncthreads();
    for (int s = 256; s > 0; s >>= 1) { if (t < s) red[t] += red[t + s]; __syncthreads(); }
    double dgsum = red[0];
    __syncthreads();

    double vr = 0.0;
    const double* Vr = &V[t * 512];
    for (int i = 0; i < 512; ++i) vr += Vr[i] * coef[i];
    v[t] = vr;

    red[t] = isfinite(vr) ? 0.0 : 1.0;
    __syncthreads();
    for (int s = 256; s > 0; s >>= 1) { if (t < s) red[t] += red[t + s]; __syncthreads(); }
    if (t == 0) {
        double f = 0.0;
        if (red[0] > 0.0) f = 2.0;
        else if (offsum > 1e-10 * dgsum) f = 5.0;
        flag[0] = f;
        flag[1] = nk;
        flag[2] = lmax;
    }
}

// --------------------------------------------------------------------------
// fused query pipeline (f64 math, f32 Ks)
// --------------------------------------------------------------------------
__global__ void mk5_query(const float* Qset, const float* Sset,
                          const float* WM1, const float* WM2, const float* bM2,
                          const float* WK1, const float* WK2, const float* bK2,
                          const double* cM, const double* cK,
                          const float* Ksf, const double* nKs,
                          const double* vv, const double* bptr,
                          const double* flag, float* out)
{
    __shared__ double hK[8][256];
    __shared__ double Kq[8][257];
    __shared__ double qx0[8], qx1[8], qm[8], nq[8];
    __shared__ double vsh[512];
    __shared__ double nss[512];
    __shared__ double redd[4];
    int t = threadIdx.x;
    int qbase = blockIdx.x * 8;

    if (t < 8) {
        qx0[t] = (double)Qset[(qbase + t) * 2];
        qx1[t] = (double)Qset[(qbase + t) * 2 + 1];
    }
    for (int i = t; i < 512; i += 256) { vsh[i] = vv[i]; nss[i] = nKs[i]; }
    __syncthreads();

    {
        int q = t >> 5, l32 = t & 31;
        double x0 = qx0[q], x1 = qx1[q];
        double pm = 0.0;
        for (int j = l32; j < 256; j += 32) {
            double aM = x0 * (double)WM1[j] + x1 * (double)WM1[256 + j] + cM[j];
            if (aM > 0.0) pm += aM * (double)WM2[j];
            double aK = x0 * (double)WK1[j] + x1 * (double)WK1[256 + j] + cK[j];
            hK[q][j] = (aK > 0.0) ? aK : 0.0;
        }
        for (int s = 16; s > 0; s >>= 1) pm += __shfl_xor(pm, s);
        if (l32 == 0) qm[q] = pm + (double)bM2[0];
    }
    __syncthreads();

    {
        double acc[8];
        #pragma unroll
        for (int q = 0; q < 8; ++q) acc[q] = 0.0;
        for (int k = 0; k < 256; ++k) {
            double w = (double)WK2[k * 256 + t];
            #pragma unroll
            for (int q = 0; q < 8; ++q) acc[q] += hK[q][k] * w;
        }
        double bk = (double)bK2[t];
        #pragma unroll
        for (int q = 0; q < 8; ++q) Kq[q][t] = acc[q] + bk;
    }
    __syncthreads();

    {
        int q = t >> 5, l32 = t & 31;
        double s = 0.0;
        for (int j = l32; j < 256; j += 32) { double e = Kq[q][j]; s += e * e; }
        for (int s2 = 16; s2 > 0; s2 >>= 1) s += __shfl_xor(s, s2);
        if (l32 == 0) nq[q] = s;
    }
    __syncthreads();

    double yacc[8];
    #pragma unroll
    for (int q = 0; q < 8; ++q) yacc[q] = 0.0;
    double b = bptr[0];
    for (int jj = 0; jj < 2; ++jj) {
        int j = jj * 256 + t;
        const float* kr = &Ksf[j * 256];
        double dacc[8];
        #pragma unroll
        for (int q = 0; q < 8; ++q) dacc[q] = 0.0;
        for (int k = 0; k < 256; ++k) {
            double kv = (double)kr[k];
            #pragma unroll
            for (int q = 0; q < 8; ++q) dacc[q] += Kq[q][k] * kv;
        }
        float sxj0 = Sset[3 * j], sxj1 = Sset[3 * j + 1];
        double nsj = nss[j], vj = vsh[j];
        #pragma unroll
        for (int q = 0; q < 8; ++q) {
            double d2 = nq[q] + nsj - 2.0 * dacc[q];
            double d = sqrt(dmx(d2, 0.0));
            double m = exp(-d);
            if ((float)qx0[q] == sxj0 && (float)qx1[q] == sxj1) m += b;
            yacc[q] += m * vj;
        }
    }

    double diag = 0.0;
    {
        double f = flag[0];
        if (f == 2.0) diag += 4e5;
        if (f == 5.0) diag += 5e5;
    }
    #pragma unroll
    for (int q = 0; q < 8; ++q) {
        double s = yacc[q];
        for (int off = 32; off > 0; off >>= 1) s += __shfl_down(s, off);
        int lane = t & 63, w = t >> 6;
        if (lane == 0) redd[w] = s;
        __syncthreads();
        if (t == 0) out[qbase + q] = (float)(qm[q] + redd[0] + redd[1] + redd[2] + redd[3] + diag);
        __syncthreads();
    }
}

// ---------------------------------------------------------------------------
extern "C" void kernel_launch(void* const* d_in, const int* in_sizes, int n_in,
                              void* d_out, int out_size, void* d_ws, size_t ws_size,
                              hipStream_t stream) {
    float* out = (float*)d_out;

    const int EXP[18] = {1536, 65536, 768, 256, 65536, 256, 65536, 256, 256, 1,
                         66048, 256, 256, 1, 66048, 256, 65536, 256};
    if (n_in != 18) {
        mk5_diag<<<(out_size + 255) / 256, 256, 0, stream>>>(out, out_size, 2.0e6f + n_in);
        return;
    }
    for (int i = 0; i < 18; ++i) {
        if (in_sizes[i] != EXP[i]) {
            mk5_diag<<<(out_size + 255) / 256, 256, 0, stream>>>(out, out_size, 1.0e6f + i * 1000.0f);
            return;
        }
    }

    const float* S   = (const float*)d_in[0];
    const float* Qs  = (const float*)d_in[1];
    const float* WZ1 = (const float*)d_in[2];  const float* bZ1 = (const float*)d_in[3];
    const float* WZ2 = (const float*)d_in[4];  const float* bZ2 = (const float*)d_in[5];
    const float* WB1 = (const float*)d_in[6];  const float* bB1 = (const float*)d_in[7];
    const float* WB2 = (const float*)d_in[8];  const float* bB2 = (const float*)d_in[9];
    const float* WM1 = (const float*)d_in[10]; const float* bM1 = (const float*)d_in[11];
    const float* WM2 = (const float*)d_in[12]; const float* bM2 = (const float*)d_in[13];
    const float* WK1 = (const float*)d_in[14]; const float* bK1 = (const float*)d_in[15];
    const float* WK2 = (const float*)d_in[16]; const float* bK2 = (const float*)d_in[17];

    // workspace (fp64 words)
    const size_t oA  = 0;                    // 262144
    const size_t oV  = oA + 262144;          // 262144
    const size_t oQ  = oV + 262144;          // 32768
    const size_t oKs = oQ + 32768;           // Ksf f32: 131072 -> 65536 dbl
    const size_t oZ  = oKs + 65536;
    const size_t oCM = oZ + 256;
    const size_t oCK = oCM + 256;
    const size_t oB  = oCK + 256;            // bsc: [0]=b, [1]=flag, [2]=nkept, [3]=lmax
    const size_t oR  = oB + 8;
    const size_t oN  = oR + 512;
    const size_t oVv = oN + 512;
    const size_t TOTW = oVv + 512;
    if (ws_size < TOTW * 8) {
        mk5_diag<<<(out_size + 255) / 256, 256, 0, stream>>>(out, out_size, (float)ws_size);
        return;
    }

    double* W   = (double*)d_ws;
    double* A   = W + oA;
    double* V   = W + oV;
    double* Qg  = W + oQ;
    float*  Ksf = (float*)(W + oKs);
    double* Z   = W + oZ;
    double* cM  = W + oCM;
    double* cK  = W + oCK;
    double* bsc = W + oB;
    double* rhs = W + oR;
    double* nKs = W + oN;
    double* v   = W + oVv;

    mk5_zb<<<1, 256, 0, stream>>>(S, WZ1, bZ1, WZ2, bZ2, WB1, bB1, WB2, bB2,
                                  WM1, bM1, WK1, bK1, Z, cM, cK, bsc);
    mk5_support<<<512, 256, 0, stream>>>(S, WM1, WM2, bM2, WK1, WK2, bK2,
                                         cM, cK, Ksf, nKs, rhs);
    mk5_selfA<<<512, 256, 0, stream>>>(S, Ksf, nKs, bsc, A);

    ej_vinit<<<(512 * 512 + 255) / 256, 256, 0, stream>>>(V);
    for (int sw = 0; sw < OUTER_SWEEPS; ++sw) {
        for (int r = 0; r < 15; ++r) {
            ej_sub<<<8, 512, 0, stream>>>(A, Qg, r);
            ej_rows<<<dim3(8, 16), 256, 0, stream>>>(A, Qg, r);
            ej_cols<<<dim3(8, 16), 256, 0, stream>>>(A, V, Qg, r);
        }
    }
    ej_assemble<<<1, 512, 0, stream>>>(A, V, rhs, v, bsc + 1);

    mk5_query<<<4096, 256, 0, stream>>>(Qs, S, WM1, WM2, bM2, WK1, WK2, bK2,
                                        cM, cK, Ksf, nKs, v, bsc, bsc + 1, out);
}